// Round 8
// baseline (203.642 us; speedup 1.0000x reference)
//
#include <hip/hip_runtime.h>

#define NN 50000
#define NE 600000
#define DIM 128
#define CAP 40

// workspace layout (~34 MB of >=256MB d_ws)
#define OFF_CUR    0         // NN ints (zeroed in k_init)
#define OFF_DINV   200704    // NN floats
#define OFF_FLAG   401408    // 1 int: is64
#define OFF_SRCL   401920    // NN*CAP ints = 8,000,000 B (pre-filled with NN)
#define OFF_W1T    8401920   // 32768 B
#define OFF_W2T    8434688   // 32768 B
#define OFF_Y      8467456   // (NN+1)*256 B bf16x2 rows; row NN = zeros
#define OFF_Z1     21267968  // (NN+1)*256 B bf16x2 rows; row NN = zeros

typedef unsigned short u16;
typedef unsigned int u32;
typedef __attribute__((ext_vector_type(8))) short short8;
typedef __attribute__((ext_vector_type(4))) float floatx4;

__device__ __forceinline__ float bflo(u32 u) { return __uint_as_float(u << 16); }
__device__ __forceinline__ float bfhi(u32 u) { return __uint_as_float(u & 0xFFFF0000u); }
__device__ __forceinline__ u16 f2bf(float f) {
    u32 x = __float_as_uint(f);
    return (u16)((x + 0x7FFFu + ((x >> 16) & 1u)) >> 16);  // RNE
}
__device__ __forceinline__ u32 pack2(float hi, float lo) {
    return ((u32)f2bf(hi) << 16) | (u32)f2bf(lo);
}

// ---- init: zero cur, pre-fill srclist with NN (virtual zero row), zero the
// two zero-rows, transpose both W (f32->bf16), sniff index width -------------
__global__ __launch_bounds__(256) void k_init(
    const int* __restrict__ ei, const float* __restrict__ W1,
    const float* __restrict__ W2, char* __restrict__ ws) {
    int* cur = (int*)(ws + OFF_CUR);
    int* flagw = (int*)(ws + OFF_FLAG);
    int4* sl4 = (int4*)(ws + OFF_SRCL);
    u16* W1t = (u16*)(ws + OFF_W1T);
    u16* W2t = (u16*)(ws + OFF_W2T);
    u32* y = (u32*)(ws + OFF_Y);
    u32* z1 = (u32*)(ws + OFF_Z1);
    int b = blockIdx.x, tid = threadIdx.x;
    int gid = b * 256 + tid;
    const int GT = 128 * 256;
    for (int i = gid; i < NN; i += GT) cur[i] = 0;
    int4 vNN = {NN, NN, NN, NN};
    for (int i = gid; i < NN * CAP / 4; i += GT) sl4[i] = vNN;
    if (b == 126 && tid < 64) y[(size_t)NN * 64 + tid] = 0u;   // zero row
    if (b == 127 && tid < 64) z1[(size_t)NN * 64 + tid] = 0u;  // zero row
    const float* W = (b < 64) ? W1 : W2;
    u16* Wt = (b < 64) ? W1t : W2t;
    int e = (b & 63) * 256 + tid;
    int k = e >> 7, n = e & 127;
    Wt[n * DIM + k] = f2bf(W[e]);
    if (b == 0) {
        // int64 indices misread as int32: odd (high) words ~all zero.
        __shared__ int sc;
        if (tid == 0) sc = 0;
        __syncthreads();
        int lc = 0;
        for (int i = tid; i < 4096; i += 256) lc += (ei[2 * i + 1] != 0) ? 1 : 0;
        if (lc) atomicAdd(&sc, lc);
        __syncthreads();
        if (tid == 0) *flagw = (sc < 64) ? 1 : 0;
    }
}

// ---- fill: fixed-capacity bucket lists; cur counts ALL edges (exact degree),
// stored srcs sanitized to [0,NN). Slots >= cnt keep NN (zero row). ----------
__global__ __launch_bounds__(256) void k_fill(const int* __restrict__ ei,
                                              char* __restrict__ ws) {
    int* cur = (int*)(ws + OFF_CUR);
    int* srclist = (int*)(ws + OFF_SRCL);
    int is64 = *(const int*)(ws + OFF_FLAG);
    int i = blockIdx.x * 256 + threadIdx.x;
    if (i >= NE) return;
    int d = is64 ? ei[2 * (NE + i)] : ei[NE + i];
    if ((u32)d >= NN) return;
    int p = atomicAdd(&cur[d], 1);
    if (p < CAP) {
        int s = is64 ? ei[2 * i] : ei[i];
        srclist[d * CAP + p] = ((u32)s < NN) ? s : 0;
    }
}

// ---- scale: dinv[n] = rsqrt(deg+1); y = bf16(dinv[row] * x) ----------------
__global__ __launch_bounds__(256) void k_scale(const float* __restrict__ x,
                                               char* __restrict__ ws) {
    const int* cur = (const int*)(ws + OFF_CUR);
    float* dinv = (float*)(ws + OFF_DINV);
    u32* y = (u32*)(ws + OFF_Y);
    int i = blockIdx.x * 256 + threadIdx.x;  // over NN*64 float2
    if (i >= NN * 64) return;
    int n = i >> 6;
    float dn = rsqrtf((float)(cur[n] + 1));  // +1 self-loop
    if ((i & 63) == 0) dinv[n] = dn;
    float2 v = ((const float2*)x)[i];
    y[i] = pack2(dn * v.y, dn * v.x);
}

// ---- fused layer: block owns 16 nodes. Gather: quarter-wave (16 lanes x
// dwordx4) per node, 4 nodes/wave in parallel; depth-6 row pipeline; tails
// read the virtual zero row (L1-hot) -> no masks/selects in the hot loop.
// Then 16x128 @ 128x128 MFMA from LDS, fused bias+relu epilogue.
// mode 0: store bf16 dinv[row]*relu(v);  mode 1: store f32 relu(v)
__global__ __launch_bounds__(256) void k_layer(
    const u32* __restrict__ y, const char* __restrict__ ws,
    const u16* __restrict__ Bt, const float* __restrict__ bias,
    void* __restrict__ out, int mode) {
    const int* cur = (const int*)(ws + OFF_CUR);
    const int* srclist = (const int*)(ws + OFF_SRCL);
    const float* dinv = (const float*)(ws + OFF_DINV);
    __shared__ u32 tl[16][68];  // row stride 272B: 16B-aligned for b128 ops
    int tid = threadIdx.x;
    int wv = tid >> 6, lane = tid & 63;
    int grp = lane >> 4, sl16 = lane & 15;
    int node0 = blockIdx.x << 4;
    int nn = wv * 4 + grp;   // tile row 0..15
    int n = node0 + nn;      // this quarter-wave's node
    int cnt = cur[n];
    cnt = cnt < CAP ? cnt : CAP;
    float dn = dinv[n];
    const int* sl = srclist + (size_t)n * CAP;

    // init accumulators from self row (always included; Ahat has self-loops)
    uint4 us = *(const uint4*)(y + (size_t)n * 64 + sl16 * 4);
    float a0 = bflo(us.x), a1 = bfhi(us.x), a2 = bflo(us.y), a3 = bfhi(us.y);
    float a4 = bflo(us.z), a5 = bfhi(us.z), a6 = bflo(us.w), a7 = bfhi(us.w);

    // wave-uniform iteration count = max cnt over the 4 groups
    int mx = cnt;
    mx = max(mx, __shfl_xor(mx, 16));
    mx = max(mx, __shfl_xor(mx, 32));

#define SIDX(j) sl[(j) < (CAP - 1) ? (j) : (CAP - 1)]  // in [0,NN]; pad = NN
#define ROW(s) (*(const uint4*)(y + (size_t)(s) * 64 + sl16 * 4))
    if (mx > 0) {
        uint4 u0 = ROW(SIDX(0)), u1 = ROW(SIDX(1)), u2 = ROW(SIDX(2));
        uint4 u3 = ROW(SIDX(3)), u4 = ROW(SIDX(4));
        int sF = SIDX(5);
#pragma unroll 2
        for (int i = 0; i < mx; ++i) {
            int sN = SIDX(i + 6);
            uint4 u5 = ROW(sF);
            a0 += bflo(u0.x); a1 += bfhi(u0.x);
            a2 += bflo(u0.y); a3 += bfhi(u0.y);
            a4 += bflo(u0.z); a5 += bfhi(u0.z);
            a6 += bflo(u0.w); a7 += bfhi(u0.w);
            u0 = u1; u1 = u2; u2 = u3; u3 = u4; u4 = u5;
            sF = sN;
        }
    }
#undef SIDX
#undef ROW
    uint4 o;
    o.x = pack2(dn * a1, dn * a0);
    o.y = pack2(dn * a3, dn * a2);
    o.z = pack2(dn * a5, dn * a4);
    o.w = pack2(dn * a7, dn * a6);
    *(uint4*)&tl[nn][sl16 * 4] = o;
    __syncthreads();

    // MFMA phase: rows 0..15 of tile @ Bt (128x128), per-wave 2 col-tiles
    int m = lane & 15, kg = lane >> 4;
    floatx4 acc[2];
    acc[0] = (floatx4){0.f, 0.f, 0.f, 0.f};
    acc[1] = (floatx4){0.f, 0.f, 0.f, 0.f};
#pragma unroll
    for (int kk = 0; kk < 4; ++kk) {
        int k0 = kk * 32 + kg * 8;  // bf16 k index
        short8 a = *(const short8*)&tl[m][kk * 16 + kg * 4];
#pragma unroll
        for (int j = 0; j < 2; ++j) {
            int nt = wv * 2 + j;
            short8 b = *(const short8*)(Bt + (size_t)(nt * 16 + m) * DIM + k0);
            acc[j] = __builtin_amdgcn_mfma_f32_16x16x32_bf16(a, b, acc[j], 0, 0, 0);
        }
    }
    float4 d4 = (mode == 0) ? *(const float4*)(dinv + node0 + kg * 4)
                            : make_float4(1.f, 1.f, 1.f, 1.f);
#pragma unroll
    for (int j = 0; j < 2; ++j) {
        int col = (wv * 2 + j) * 16 + m;
        float bv = bias[col];
#pragma unroll
        for (int r = 0; r < 4; ++r) {
            int row = node0 + kg * 4 + r;  // C/D: col=lane&15, row=(lane>>4)*4+reg
            float v = acc[j][r] + bv;
            v = v > 0.f ? v : 0.f;
            if (mode == 0)
                ((u16*)out)[(size_t)row * DIM + col] = f2bf(v * (&d4.x)[r]);
            else
                ((float*)out)[(size_t)row * DIM + col] = v;
        }
    }
}

extern "C" void kernel_launch(void* const* d_in, const int* in_sizes, int n_in,
                              void* d_out, int out_size, void* d_ws, size_t ws_size,
                              hipStream_t stream) {
    (void)in_sizes; (void)n_in; (void)out_size; (void)ws_size;
    const float* x  = (const float*)d_in[0];
    const int*   ei = (const int*)d_in[1];
    const float* W1 = (const float*)d_in[2];
    const float* b1 = (const float*)d_in[3];
    const float* W2 = (const float*)d_in[4];
    const float* b2 = (const float*)d_in[5];
    char* ws = (char*)d_ws;

    u16* W1t = (u16*)(ws + OFF_W1T);
    u16* W2t = (u16*)(ws + OFF_W2T);
    u32* y   = (u32*)(ws + OFF_Y);
    u32* z1  = (u32*)(ws + OFF_Z1);

    k_init<<<128, 256, 0, stream>>>(ei, W1, W2, ws);
    k_fill<<<(NE + 255) / 256, 256, 0, stream>>>(ei, ws);
    k_scale<<<(NN * 64 + 255) / 256, 256, 0, stream>>>(x, ws);
    // layer 1: z1 = dinv * relu(Ahat(y) @ W1 + b1)   (bf16, pre-scaled)
    k_layer<<<NN / 16, 256, 0, stream>>>(y, ws, W1t, b1, z1, 0);
    // layer 2: out = relu(Ahat(z1) @ W2 + b2)        (f32)
    k_layer<<<NN / 16, 256, 0, stream>>>(z1, ws, W2t, b2, d_out, 1);
}

// Round 9
// 203.330 us; speedup vs baseline: 1.0015x; 1.0015x over previous
//
#include <hip/hip_runtime.h>

#define NN 50000
#define NE 600000
#define DIM 128
#define CAP 40

// workspace layout (~34 MB of >=256MB d_ws)
#define OFF_CUR    0         // NN ints (zeroed in k_init)
#define OFF_DINV   200704    // NN floats
#define OFF_FLAG   401408    // 1 int: is64
#define OFF_SRCL   401920    // NN*CAP ints (slots >= cnt stay poison; clamped at read)
#define OFF_W1T    8401920   // 32768 B
#define OFF_W2T    8434688   // 32768 B
#define OFF_Y      8467456   // (NN+1)*256 B bf16x2 rows; row NN zeroed in k_scale
#define OFF_Z1     21267968  // (NN+1)*256 B bf16x2 rows; row NN zeroed in k_scale

typedef unsigned short u16;
typedef unsigned int u32;
typedef __attribute__((ext_vector_type(8))) short short8;
typedef __attribute__((ext_vector_type(4))) float floatx4;

__device__ __forceinline__ float bflo(u32 u) { return __uint_as_float(u << 16); }
__device__ __forceinline__ float bfhi(u32 u) { return __uint_as_float(u & 0xFFFF0000u); }
__device__ __forceinline__ u16 f2bf(float f) {
    u32 x = __float_as_uint(f);
    return (u16)((x + 0x7FFFu + ((x >> 16) & 1u)) >> 16);  // RNE
}
__device__ __forceinline__ u32 pack2(float hi, float lo) {
    return ((u32)f2bf(hi) << 16) | (u32)f2bf(lo);
}

// ---- init: zero cur, transpose both W (f32->bf16), sniff index width --------
__global__ __launch_bounds__(256) void k_init(
    const int* __restrict__ ei, const float* __restrict__ W1,
    const float* __restrict__ W2, char* __restrict__ ws) {
    int* cur = (int*)(ws + OFF_CUR);
    int* flagw = (int*)(ws + OFF_FLAG);
    u16* W1t = (u16*)(ws + OFF_W1T);
    u16* W2t = (u16*)(ws + OFF_W2T);
    int b = blockIdx.x, tid = threadIdx.x;
    for (int i = b * 256 + tid; i < NN; i += 128 * 256) cur[i] = 0;
    const float* W = (b < 64) ? W1 : W2;
    u16* Wt = (b < 64) ? W1t : W2t;
    int e = (b & 63) * 256 + tid;
    int k = e >> 7, n = e & 127;
    Wt[n * DIM + k] = f2bf(W[e]);
    if (b == 0) {
        // int64 indices misread as int32: odd (high) words ~all zero.
        __shared__ int sc;
        if (tid == 0) sc = 0;
        __syncthreads();
        int lc = 0;
        for (int i = tid; i < 4096; i += 256) lc += (ei[2 * i + 1] != 0) ? 1 : 0;
        if (lc) atomicAdd(&sc, lc);
        __syncthreads();
        if (tid == 0) *flagw = (sc < 64) ? 1 : 0;
    }
}

// ---- fill: fixed-capacity bucket lists; cur counts ALL edges (exact degree),
// stored srcs sanitized to [0,NN). Overflow beyond CAP dropped (P ~ 1e-11). --
__global__ __launch_bounds__(256) void k_fill(const int* __restrict__ ei,
                                              char* __restrict__ ws) {
    int* cur = (int*)(ws + OFF_CUR);
    int* srclist = (int*)(ws + OFF_SRCL);
    int is64 = *(const int*)(ws + OFF_FLAG);
    int i = blockIdx.x * 256 + threadIdx.x;
    if (i >= NE) return;
    int d = is64 ? ei[2 * (NE + i)] : ei[NE + i];
    if ((u32)d >= NN) return;
    int p = atomicAdd(&cur[d], 1);
    if (p < CAP) {
        int s = is64 ? ei[2 * i] : ei[i];
        srclist[d * CAP + p] = ((u32)s < NN) ? s : 0;
    }
}

// ---- scale: dinv[n] = rsqrt(deg+1); y = bf16(dinv[row] * x); also zeroes the
// virtual zero-rows (index NN) of both y and z1 ------------------------------
__global__ __launch_bounds__(256) void k_scale(const float* __restrict__ x,
                                               char* __restrict__ ws) {
    const int* cur = (const int*)(ws + OFF_CUR);
    float* dinv = (float*)(ws + OFF_DINV);
    u32* y = (u32*)(ws + OFF_Y);
    u32* z1 = (u32*)(ws + OFF_Z1);
    int i = blockIdx.x * 256 + threadIdx.x;  // over NN*64 float2 (+tail block)
    if (i >= NN * 64) {
        int j = i - NN * 64;
        if (j < 64) y[(size_t)NN * 64 + j] = 0u;
        else if (j < 128) z1[(size_t)NN * 64 + (j - 64)] = 0u;
        return;
    }
    int n = i >> 6;
    float dn = rsqrtf((float)(cur[n] + 1));  // +1 self-loop
    if ((i & 63) == 0) dinv[n] = dn;
    float2 v = ((const float2*)x)[i];
    y[i] = pack2(dn * v.y, dn * v.x);
}

// ---- fused layer: block owns 16 nodes. Gather: quarter-wave (16 lanes x
// dwordx4) per node, 4 nodes/wave in parallel; chunk-of-4 rows per iteration
// (int4 index load, clamp pad slots to zero-row NN, 4 row loads, 32 adds).
// Plain loop => compiler renames regs across unrolled bodies (no shift movs).
// Then 16x128 @ 128x128 MFMA from LDS, fused bias+relu epilogue.
// mode 0: store bf16 dinv[row]*relu(v);  mode 1: store f32 relu(v)
__global__ __launch_bounds__(256) void k_layer(
    const u32* __restrict__ y, const char* __restrict__ ws,
    const u16* __restrict__ Bt, const float* __restrict__ bias,
    void* __restrict__ out, int mode) {
    const int* cur = (const int*)(ws + OFF_CUR);
    const int* srclist = (const int*)(ws + OFF_SRCL);
    const float* dinv = (const float*)(ws + OFF_DINV);
    __shared__ u32 tl[16][68];  // row stride 272B: 16B-aligned for b128 ops
    int tid = threadIdx.x;
    int wv = tid >> 6, lane = tid & 63;
    int grp = lane >> 4, sl16 = lane & 15;
    int node0 = blockIdx.x << 4;
    int nn = wv * 4 + grp;   // tile row 0..15
    int n = node0 + nn;      // this quarter-wave's node
    int cnt = cur[n];
    cnt = cnt < CAP ? cnt : CAP;
    float dn = dinv[n];
    const int* sl = srclist + (size_t)n * CAP;

    // init accumulators from self row (always included; Ahat has self-loops)
    uint4 us = *(const uint4*)(y + (size_t)n * 64 + sl16 * 4);
    float a0 = bflo(us.x), a1 = bfhi(us.x), a2 = bflo(us.y), a3 = bfhi(us.y);
    float a4 = bflo(us.z), a5 = bfhi(us.z), a6 = bflo(us.w), a7 = bfhi(us.w);

    // wave-uniform chunk count = ceil(max cnt over 4 groups / 4)
    int mx = cnt;
    mx = max(mx, __shfl_xor(mx, 16));
    mx = max(mx, __shfl_xor(mx, 32));
    int chunks = (mx + 3) >> 2;

#define ROW(s) (*(const uint4*)(y + (size_t)(s) * 64 + sl16 * 4))
#pragma unroll 2
    for (int c = 0; c < chunks; ++c) {
        int j = c * 4;
        int4 s = *(const int4*)(sl + j);        // 16B idx load (may hit poison)
        s.x = (j + 0 < cnt) ? s.x : NN;         // pad/poison -> zero row
        s.y = (j + 1 < cnt) ? s.y : NN;
        s.z = (j + 2 < cnt) ? s.z : NN;
        s.w = (j + 3 < cnt) ? s.w : NN;
        uint4 v0 = ROW(s.x), v1 = ROW(s.y), v2 = ROW(s.z), v3 = ROW(s.w);
        a0 += bflo(v0.x); a1 += bfhi(v0.x); a2 += bflo(v0.y); a3 += bfhi(v0.y);
        a4 += bflo(v0.z); a5 += bfhi(v0.z); a6 += bflo(v0.w); a7 += bfhi(v0.w);
        a0 += bflo(v1.x); a1 += bfhi(v1.x); a2 += bflo(v1.y); a3 += bfhi(v1.y);
        a4 += bflo(v1.z); a5 += bfhi(v1.z); a6 += bflo(v1.w); a7 += bfhi(v1.w);
        a0 += bflo(v2.x); a1 += bfhi(v2.x); a2 += bflo(v2.y); a3 += bfhi(v2.y);
        a4 += bflo(v2.z); a5 += bfhi(v2.z); a6 += bflo(v2.w); a7 += bfhi(v2.w);
        a0 += bflo(v3.x); a1 += bfhi(v3.x); a2 += bflo(v3.y); a3 += bfhi(v3.y);
        a4 += bflo(v3.z); a5 += bfhi(v3.z); a6 += bflo(v3.w); a7 += bfhi(v3.w);
    }
#undef ROW
    uint4 o;
    o.x = pack2(dn * a1, dn * a0);
    o.y = pack2(dn * a3, dn * a2);
    o.z = pack2(dn * a5, dn * a4);
    o.w = pack2(dn * a7, dn * a6);
    *(uint4*)&tl[nn][sl16 * 4] = o;
    __syncthreads();

    // MFMA phase: rows 0..15 of tile @ Bt (128x128), per-wave 2 col-tiles
    int m = lane & 15, kg = lane >> 4;
    floatx4 acc[2];
    acc[0] = (floatx4){0.f, 0.f, 0.f, 0.f};
    acc[1] = (floatx4){0.f, 0.f, 0.f, 0.f};
#pragma unroll
    for (int kk = 0; kk < 4; ++kk) {
        int k0 = kk * 32 + kg * 8;  // bf16 k index
        short8 a = *(const short8*)&tl[m][kk * 16 + kg * 4];
#pragma unroll
        for (int j = 0; j < 2; ++j) {
            int nt = wv * 2 + j;
            short8 b = *(const short8*)(Bt + (size_t)(nt * 16 + m) * DIM + k0);
            acc[j] = __builtin_amdgcn_mfma_f32_16x16x32_bf16(a, b, acc[j], 0, 0, 0);
        }
    }
    float4 d4 = (mode == 0) ? *(const float4*)(dinv + node0 + kg * 4)
                            : make_float4(1.f, 1.f, 1.f, 1.f);
#pragma unroll
    for (int j = 0; j < 2; ++j) {
        int col = (wv * 2 + j) * 16 + m;
        float bv = bias[col];
#pragma unroll
        for (int r = 0; r < 4; ++r) {
            int row = node0 + kg * 4 + r;  // C/D: col=lane&15, row=(lane>>4)*4+reg
            float v = acc[j][r] + bv;
            v = v > 0.f ? v : 0.f;
            if (mode == 0)
                ((u16*)out)[(size_t)row * DIM + col] = f2bf(v * (&d4.x)[r]);
            else
                ((float*)out)[(size_t)row * DIM + col] = v;
        }
    }
}

extern "C" void kernel_launch(void* const* d_in, const int* in_sizes, int n_in,
                              void* d_out, int out_size, void* d_ws, size_t ws_size,
                              hipStream_t stream) {
    (void)in_sizes; (void)n_in; (void)out_size; (void)ws_size;
    const float* x  = (const float*)d_in[0];
    const int*   ei = (const int*)d_in[1];
    const float* W1 = (const float*)d_in[2];
    const float* b1 = (const float*)d_in[3];
    const float* W2 = (const float*)d_in[4];
    const float* b2 = (const float*)d_in[5];
    char* ws = (char*)d_ws;

    u16* W1t = (u16*)(ws + OFF_W1T);
    u16* W2t = (u16*)(ws + OFF_W2T);
    u32* y   = (u32*)(ws + OFF_Y);
    u32* z1  = (u32*)(ws + OFF_Z1);

    k_init<<<128, 256, 0, stream>>>(ei, W1, W2, ws);
    k_fill<<<(NE + 255) / 256, 256, 0, stream>>>(ei, ws);
    k_scale<<<NN * 64 / 256 + 1, 256, 0, stream>>>(x, ws);
    // layer 1: z1 = dinv * relu(Ahat(y) @ W1 + b1)   (bf16, pre-scaled)
    k_layer<<<NN / 16, 256, 0, stream>>>(y, ws, W1t, b1, z1, 0);
    // layer 2: out = relu(Ahat(z1) @ W2 + b2)        (f32)
    k_layer<<<NN / 16, 256, 0, stream>>>(z1, ws, W2t, b2, d_out, 1);
}

// Round 10
// 195.637 us; speedup vs baseline: 1.0409x; 1.0393x over previous
//
#include <hip/hip_runtime.h>

#define NN 50000
#define NE 600000
#define DIM 128
#define CAP 40

// workspace layout (~34 MB of >=256MB d_ws)
#define OFF_CUR    0         // NN ints (zeroed in k_init)
#define OFF_DINV   200704    // NN floats
#define OFF_FLAG   401408    // 1 int: is64
#define OFF_SRCL   401920    // NN*CAP ints (slots >= cnt unread: gather masks by cnt)
#define OFF_W1T    8401920   // 32768 B
#define OFF_W2T    8434688   // 32768 B
#define OFF_Y      8467456   // NN*256 B bf16x2 rows
#define OFF_Z1     21267968  // NN*256 B bf16x2 rows (dinv-prescaled)

typedef unsigned short u16;
typedef unsigned int u32;
typedef __attribute__((ext_vector_type(8))) short short8;
typedef __attribute__((ext_vector_type(4))) float floatx4;

__device__ __forceinline__ float bflo(u32 u) { return __uint_as_float(u << 16); }
__device__ __forceinline__ float bfhi(u32 u) { return __uint_as_float(u & 0xFFFF0000u); }
__device__ __forceinline__ u16 f2bf(float f) {
    u32 x = __float_as_uint(f);
    return (u16)((x + 0x7FFFu + ((x >> 16) & 1u)) >> 16);  // RNE
}
__device__ __forceinline__ u32 pack2(float hi, float lo) {
    return ((u32)f2bf(hi) << 16) | (u32)f2bf(lo);
}

// ---- init: zero cur, transpose both W (f32->bf16), sniff index width --------
__global__ __launch_bounds__(256) void k_init(
    const int* __restrict__ ei, const float* __restrict__ W1,
    const float* __restrict__ W2, char* __restrict__ ws) {
    int* cur = (int*)(ws + OFF_CUR);
    int* flagw = (int*)(ws + OFF_FLAG);
    u16* W1t = (u16*)(ws + OFF_W1T);
    u16* W2t = (u16*)(ws + OFF_W2T);
    int b = blockIdx.x, tid = threadIdx.x;
    for (int i = b * 256 + tid; i < NN; i += 128 * 256) cur[i] = 0;
    const float* W = (b < 64) ? W1 : W2;
    u16* Wt = (b < 64) ? W1t : W2t;
    int e = (b & 63) * 256 + tid;
    int k = e >> 7, n = e & 127;
    Wt[n * DIM + k] = f2bf(W[e]);
    if (b == 0) {
        // int64 indices misread as int32: odd (high) words ~all zero.
        __shared__ int sc;
        if (tid == 0) sc = 0;
        __syncthreads();
        int lc = 0;
        for (int i = tid; i < 1024; i += 256) lc += (ei[2 * i + 1] != 0) ? 1 : 0;
        if (lc) atomicAdd(&sc, lc);
        __syncthreads();
        if (tid == 0) *flagw = (sc < 16) ? 1 : 0;
    }
}

// ---- fill: 4 edges/thread, int4 loads; fixed-capacity bucket lists.
// cur counts ALL edges (exact degree); stored srcs sanitized to [0,NN);
// overflow beyond CAP dropped (P ~ 1e-11).
__global__ __launch_bounds__(256) void k_fill(const int* __restrict__ ei,
                                              char* __restrict__ ws) {
    int* cur = (int*)(ws + OFF_CUR);
    int* srclist = (int*)(ws + OFF_SRCL);
    int is64 = *(const int*)(ws + OFF_FLAG);
    int j = (blockIdx.x * 256 + threadIdx.x) * 4;
    if (j >= NE) return;  // NE % 4 == 0: full quads only
    int4 d4, s4;
    if (is64) {
        int4 a = *(const int4*)(ei + 2 * (NE + j));      // dst j, j+1 (2 x i64)
        int4 b = *(const int4*)(ei + 2 * (NE + j) + 4);  // dst j+2, j+3
        d4.x = a.x; d4.y = a.z; d4.z = b.x; d4.w = b.z;  // low halves
        int4 c = *(const int4*)(ei + 2 * j);
        int4 e = *(const int4*)(ei + 2 * j + 4);
        s4.x = c.x; s4.y = c.z; s4.z = e.x; s4.w = e.z;
    } else {
        d4 = *(const int4*)(ei + NE + j);
        s4 = *(const int4*)(ei + j);
    }
#pragma unroll
    for (int q = 0; q < 4; ++q) {
        int d = (&d4.x)[q];
        if ((u32)d >= NN) continue;
        int p = atomicAdd(&cur[d], 1);
        if (p < CAP) {
            int s = (&s4.x)[q];
            srclist[d * CAP + p] = ((u32)s < NN) ? s : 0;
        }
    }
}

// ---- scale: dinv[n] = rsqrt(deg+1); y = bf16(dinv[row] * x), float4 loads --
__global__ __launch_bounds__(256) void k_scale(const float* __restrict__ x,
                                               char* __restrict__ ws) {
    const int* cur = (const int*)(ws + OFF_CUR);
    float* dinv = (float*)(ws + OFF_DINV);
    u32* y = (u32*)(ws + OFF_Y);
    int i = blockIdx.x * 256 + threadIdx.x;  // over NN*32 float4
    if (i >= NN * 32) return;
    int n = i >> 5;
    float dn = rsqrtf((float)(cur[n] + 1));  // +1 self-loop
    if ((i & 31) == 0) dinv[n] = dn;
    float4 v = ((const float4*)x)[i];
    uint2 o;
    o.x = pack2(dn * v.y, dn * v.x);
    o.y = pack2(dn * v.w, dn * v.z);
    ((uint2*)y)[i] = o;
}

// ---- fused layer (round-7 best-measured form): block owns 16 nodes.
// Gather: quarter-wave (16 lanes x dwordx4) per node, 4 nodes/wave in
// parallel; depth-4 row pipeline + idx prefetch; masked tails read self row.
// Then 16x128 @ 128x128 MFMA from LDS, fused bias+relu epilogue.
// mode 0: store bf16 dinv[row]*relu(v);  mode 1: store f32 relu(v)
__global__ __launch_bounds__(256) void k_layer(
    const u32* __restrict__ y, const char* __restrict__ ws,
    const u16* __restrict__ Bt, const float* __restrict__ bias,
    void* __restrict__ out, int mode) {
    const int* cur = (const int*)(ws + OFF_CUR);
    const int* srclist = (const int*)(ws + OFF_SRCL);
    const float* dinv = (const float*)(ws + OFF_DINV);
    __shared__ u32 tl[16][68];  // row stride 272B: 16B-aligned for b128 ops
    int tid = threadIdx.x;
    int wv = tid >> 6, lane = tid & 63;
    int grp = lane >> 4, sl16 = lane & 15;
    int node0 = blockIdx.x << 4;
    int nn = wv * 4 + grp;   // tile row 0..15
    int n = node0 + nn;      // this quarter-wave's node
    int cnt = cur[n];
    cnt = cnt < CAP ? cnt : CAP;
    float dn = dinv[n];
    const int* sl = srclist + (size_t)n * CAP;
    int c1 = cnt > 0 ? cnt - 1 : 0;

    // init accumulators from self row (always included; Ahat has self-loops)
    uint4 us = *(const uint4*)(y + (size_t)n * 64 + sl16 * 4);
    float a0 = bflo(us.x), a1 = bfhi(us.x), a2 = bflo(us.y), a3 = bfhi(us.y);
    float a4 = bflo(us.z), a5 = bfhi(us.z), a6 = bflo(us.w), a7 = bfhi(us.w);

    // wave-uniform iteration count = max cnt over the 4 groups
    int mx = cnt;
    mx = max(mx, __shfl_xor(mx, 16));
    mx = max(mx, __shfl_xor(mx, 32));

#define SIDX(j) ((j) < cnt ? sl[(j) < c1 ? (j) : c1] : n)  // safe: [0,NN) or self
#define ROW(s) (*(const uint4*)(y + (size_t)(s) * 64 + sl16 * 4))
#define MSK(j) (((j) < cnt) ? 0xFFFFFFFFu : 0u)
    if (mx > 0) {
        int s0 = SIDX(0), s1 = SIDX(1), s2 = SIDX(2), s3 = SIDX(3);
        u32 m0 = MSK(0), m1 = MSK(1), m2 = MSK(2), m3 = MSK(3);
        uint4 u0 = ROW(s0), u1 = ROW(s1), u2 = ROW(s2);
        int sF = s3;  // index for row position i+3, fetched one iter ahead
#pragma unroll 2
        for (int i = 0; i < mx; ++i) {
            int sN = SIDX(i + 4);
            uint4 u3 = ROW(sF);
            u32 v;
            v = u0.x & m0; a0 += bflo(v); a1 += bfhi(v);
            v = u0.y & m0; a2 += bflo(v); a3 += bfhi(v);
            v = u0.z & m0; a4 += bflo(v); a5 += bfhi(v);
            v = u0.w & m0; a6 += bflo(v); a7 += bfhi(v);
            u0 = u1; u1 = u2; u2 = u3;
            m0 = m1; m1 = m2; m2 = m3; m3 = MSK(i + 4);
            sF = sN;
        }
    }
#undef SIDX
#undef ROW
#undef MSK
    uint4 o;
    o.x = pack2(dn * a1, dn * a0);
    o.y = pack2(dn * a3, dn * a2);
    o.z = pack2(dn * a5, dn * a4);
    o.w = pack2(dn * a7, dn * a6);
    *(uint4*)&tl[nn][sl16 * 4] = o;
    __syncthreads();

    // MFMA phase: rows 0..15 of tile @ Bt (128x128), per-wave 2 col-tiles
    int m = lane & 15, kg = lane >> 4;
    floatx4 acc[2];
    acc[0] = (floatx4){0.f, 0.f, 0.f, 0.f};
    acc[1] = (floatx4){0.f, 0.f, 0.f, 0.f};
#pragma unroll
    for (int kk = 0; kk < 4; ++kk) {
        int k0 = kk * 32 + kg * 8;  // bf16 k index
        short8 a = *(const short8*)&tl[m][kk * 16 + kg * 4];
#pragma unroll
        for (int j = 0; j < 2; ++j) {
            int nt = wv * 2 + j;
            short8 b = *(const short8*)(Bt + (size_t)(nt * 16 + m) * DIM + k0);
            acc[j] = __builtin_amdgcn_mfma_f32_16x16x32_bf16(a, b, acc[j], 0, 0, 0);
        }
    }
    float4 d4 = (mode == 0) ? *(const float4*)(dinv + node0 + kg * 4)
                            : make_float4(1.f, 1.f, 1.f, 1.f);
#pragma unroll
    for (int j = 0; j < 2; ++j) {
        int col = (wv * 2 + j) * 16 + m;
        float bv = bias[col];
#pragma unroll
        for (int r = 0; r < 4; ++r) {
            int row = node0 + kg * 4 + r;  // C/D: col=lane&15, row=(lane>>4)*4+reg
            float v = acc[j][r] + bv;
            v = v > 0.f ? v : 0.f;
            if (mode == 0)
                ((u16*)out)[(size_t)row * DIM + col] = f2bf(v * (&d4.x)[r]);
            else
                ((float*)out)[(size_t)row * DIM + col] = v;
        }
    }
}

extern "C" void kernel_launch(void* const* d_in, const int* in_sizes, int n_in,
                              void* d_out, int out_size, void* d_ws, size_t ws_size,
                              hipStream_t stream) {
    (void)in_sizes; (void)n_in; (void)out_size; (void)ws_size;
    const float* x  = (const float*)d_in[0];
    const int*   ei = (const int*)d_in[1];
    const float* W1 = (const float*)d_in[2];
    const float* b1 = (const float*)d_in[3];
    const float* W2 = (const float*)d_in[4];
    const float* b2 = (const float*)d_in[5];
    char* ws = (char*)d_ws;

    u16* W1t = (u16*)(ws + OFF_W1T);
    u16* W2t = (u16*)(ws + OFF_W2T);
    u32* y   = (u32*)(ws + OFF_Y);
    u32* z1  = (u32*)(ws + OFF_Z1);

    k_init<<<128, 256, 0, stream>>>(ei, W1, W2, ws);
    k_fill<<<(NE / 4 + 255) / 256, 256, 0, stream>>>(ei, ws);
    k_scale<<<NN * 32 / 256, 256, 0, stream>>>(x, ws);
    // layer 1: z1 = dinv * relu(Ahat(y) @ W1 + b1)   (bf16, pre-scaled)
    k_layer<<<NN / 16, 256, 0, stream>>>(y, ws, W1t, b1, z1, 0);
    // layer 2: out = relu(Ahat(z1) @ W2 + b2)        (f32)
    k_layer<<<NN / 16, 256, 0, stream>>>(z1, ws, W2t, b2, d_out, 1);
}

// Round 11
// 194.203 us; speedup vs baseline: 1.0486x; 1.0074x over previous
//
#include <hip/hip_runtime.h>

#define NN 50000
#define NE 600000
#define DIM 128
#define CAP 40

// workspace layout (~34 MB of >=256MB d_ws)
#define OFF_CUR    0         // NN ints (zeroed in k_init)
#define OFF_DINV   200704    // NN floats
#define OFF_FLAG   401408    // 1 int: is64
#define OFF_SRCL   401920    // NN*CAP ints (slots >= cnt unread: gather masks by cnt)
#define OFF_W1T    8401920   // 32768 B
#define OFF_W2T    8434688   // 32768 B
#define OFF_Y      8467456   // NN*256 B bf16x2 rows
#define OFF_Z1     21267968  // NN*256 B bf16x2 rows (dinv-prescaled)

typedef unsigned short u16;
typedef unsigned int u32;
typedef __attribute__((ext_vector_type(8))) short short8;
typedef __attribute__((ext_vector_type(4))) float floatx4;

__device__ __forceinline__ float bflo(u32 u) { return __uint_as_float(u << 16); }
__device__ __forceinline__ float bfhi(u32 u) { return __uint_as_float(u & 0xFFFF0000u); }
__device__ __forceinline__ u16 f2bf(float f) {
    u32 x = __float_as_uint(f);
    return (u16)((x + 0x7FFFu + ((x >> 16) & 1u)) >> 16);  // RNE
}
__device__ __forceinline__ u32 pack2(float hi, float lo) {
    return ((u32)f2bf(hi) << 16) | (u32)f2bf(lo);
}

// ---- init: zero cur, transpose both W (f32->bf16), sniff index width --------
__global__ __launch_bounds__(256) void k_init(
    const int* __restrict__ ei, const float* __restrict__ W1,
    const float* __restrict__ W2, char* __restrict__ ws) {
    int* cur = (int*)(ws + OFF_CUR);
    int* flagw = (int*)(ws + OFF_FLAG);
    u16* W1t = (u16*)(ws + OFF_W1T);
    u16* W2t = (u16*)(ws + OFF_W2T);
    int b = blockIdx.x, tid = threadIdx.x;
    for (int i = b * 256 + tid; i < NN; i += 128 * 256) cur[i] = 0;
    const float* W = (b < 64) ? W1 : W2;
    u16* Wt = (b < 64) ? W1t : W2t;
    int e = (b & 63) * 256 + tid;
    int k = e >> 7, n = e & 127;
    Wt[n * DIM + k] = f2bf(W[e]);
    if (b == 0) {
        // int64 indices misread as int32: odd (high) words ~all zero.
        __shared__ int sc;
        if (tid == 0) sc = 0;
        __syncthreads();
        int lc = 0;
        for (int i = tid; i < 1024; i += 256) lc += (ei[2 * i + 1] != 0) ? 1 : 0;
        if (lc) atomicAdd(&sc, lc);
        __syncthreads();
        if (tid == 0) *flagw = (sc < 16) ? 1 : 0;
    }
}

// ---- fill: 1 thread/edge (max TLP to hide atomic latency — the 4-edge/thread
// variant measured 46 µs vs ~20 here: atomic-latency-bound kernels need
// threads, not batching). cur counts ALL edges (exact degree); stored srcs
// sanitized to [0,NN); overflow beyond CAP dropped (P ~ 1e-11).
__global__ __launch_bounds__(256) void k_fill(const int* __restrict__ ei,
                                              char* __restrict__ ws) {
    int* cur = (int*)(ws + OFF_CUR);
    int* srclist = (int*)(ws + OFF_SRCL);
    int is64 = *(const int*)(ws + OFF_FLAG);
    int i = blockIdx.x * 256 + threadIdx.x;
    if (i >= NE) return;
    int d = is64 ? ei[2 * (NE + i)] : ei[NE + i];
    if ((u32)d >= NN) return;
    int p = atomicAdd(&cur[d], 1);
    if (p < CAP) {
        int s = is64 ? ei[2 * i] : ei[i];
        srclist[d * CAP + p] = ((u32)s < NN) ? s : 0;
    }
}

// ---- scale: dinv[n] = rsqrt(deg+1); y = bf16(dinv[row] * x), float4 loads --
__global__ __launch_bounds__(256) void k_scale(const float* __restrict__ x,
                                               char* __restrict__ ws) {
    const int* cur = (const int*)(ws + OFF_CUR);
    float* dinv = (float*)(ws + OFF_DINV);
    u32* y = (u32*)(ws + OFF_Y);
    int i = blockIdx.x * 256 + threadIdx.x;  // over NN*32 float4
    if (i >= NN * 32) return;
    int n = i >> 5;
    float dn = rsqrtf((float)(cur[n] + 1));  // +1 self-loop
    if ((i & 31) == 0) dinv[n] = dn;
    float4 v = ((const float4*)x)[i];
    uint2 o;
    o.x = pack2(dn * v.y, dn * v.x);
    o.y = pack2(dn * v.w, dn * v.z);
    ((uint2*)y)[i] = o;
}

// ---- fused layer (round-7 best-measured form): block owns 16 nodes.
// Gather: quarter-wave (16 lanes x dwordx4) per node, 4 nodes/wave in
// parallel; depth-4 row pipeline + idx prefetch; masked tails read self row.
// Then 16x128 @ 128x128 MFMA from LDS, fused bias+relu epilogue.
// mode 0: store bf16 dinv[row]*relu(v);  mode 1: store f32 relu(v)
__global__ __launch_bounds__(256) void k_layer(
    const u32* __restrict__ y, const char* __restrict__ ws,
    const u16* __restrict__ Bt, const float* __restrict__ bias,
    void* __restrict__ out, int mode) {
    const int* cur = (const int*)(ws + OFF_CUR);
    const int* srclist = (const int*)(ws + OFF_SRCL);
    const float* dinv = (const float*)(ws + OFF_DINV);
    __shared__ u32 tl[16][68];  // row stride 272B: 16B-aligned for b128 ops
    int tid = threadIdx.x;
    int wv = tid >> 6, lane = tid & 63;
    int grp = lane >> 4, sl16 = lane & 15;
    int node0 = blockIdx.x << 4;
    int nn = wv * 4 + grp;   // tile row 0..15
    int n = node0 + nn;      // this quarter-wave's node
    int cnt = cur[n];
    cnt = cnt < CAP ? cnt : CAP;
    float dn = dinv[n];
    const int* sl = srclist + (size_t)n * CAP;
    int c1 = cnt > 0 ? cnt - 1 : 0;

    // init accumulators from self row (always included; Ahat has self-loops)
    uint4 us = *(const uint4*)(y + (size_t)n * 64 + sl16 * 4);
    float a0 = bflo(us.x), a1 = bfhi(us.x), a2 = bflo(us.y), a3 = bfhi(us.y);
    float a4 = bflo(us.z), a5 = bfhi(us.z), a6 = bflo(us.w), a7 = bfhi(us.w);

    // wave-uniform iteration count = max cnt over the 4 groups
    int mx = cnt;
    mx = max(mx, __shfl_xor(mx, 16));
    mx = max(mx, __shfl_xor(mx, 32));

#define SIDX(j) ((j) < cnt ? sl[(j) < c1 ? (j) : c1] : n)  // safe: [0,NN) or self
#define ROW(s) (*(const uint4*)(y + (size_t)(s) * 64 + sl16 * 4))
#define MSK(j) (((j) < cnt) ? 0xFFFFFFFFu : 0u)
    if (mx > 0) {
        int s0 = SIDX(0), s1 = SIDX(1), s2 = SIDX(2), s3 = SIDX(3);
        u32 m0 = MSK(0), m1 = MSK(1), m2 = MSK(2), m3 = MSK(3);
        uint4 u0 = ROW(s0), u1 = ROW(s1), u2 = ROW(s2);
        int sF = s3;  // index for row position i+3, fetched one iter ahead
#pragma unroll 2
        for (int i = 0; i < mx; ++i) {
            int sN = SIDX(i + 4);
            uint4 u3 = ROW(sF);
            u32 v;
            v = u0.x & m0; a0 += bflo(v); a1 += bfhi(v);
            v = u0.y & m0; a2 += bflo(v); a3 += bfhi(v);
            v = u0.z & m0; a4 += bflo(v); a5 += bfhi(v);
            v = u0.w & m0; a6 += bflo(v); a7 += bfhi(v);
            u0 = u1; u1 = u2; u2 = u3;
            m0 = m1; m1 = m2; m2 = m3; m3 = MSK(i + 4);
            sF = sN;
        }
    }
#undef SIDX
#undef ROW
#undef MSK
    uint4 o;
    o.x = pack2(dn * a1, dn * a0);
    o.y = pack2(dn * a3, dn * a2);
    o.z = pack2(dn * a5, dn * a4);
    o.w = pack2(dn * a7, dn * a6);
    *(uint4*)&tl[nn][sl16 * 4] = o;
    __syncthreads();

    // MFMA phase: rows 0..15 of tile @ Bt (128x128), per-wave 2 col-tiles
    int m = lane & 15, kg = lane >> 4;
    floatx4 acc[2];
    acc[0] = (floatx4){0.f, 0.f, 0.f, 0.f};
    acc[1] = (floatx4){0.f, 0.f, 0.f, 0.f};
#pragma unroll
    for (int kk = 0; kk < 4; ++kk) {
        int k0 = kk * 32 + kg * 8;  // bf16 k index
        short8 a = *(const short8*)&tl[m][kk * 16 + kg * 4];
#pragma unroll
        for (int j = 0; j < 2; ++j) {
            int nt = wv * 2 + j;
            short8 b = *(const short8*)(Bt + (size_t)(nt * 16 + m) * DIM + k0);
            acc[j] = __builtin_amdgcn_mfma_f32_16x16x32_bf16(a, b, acc[j], 0, 0, 0);
        }
    }
    float4 d4 = (mode == 0) ? *(const float4*)(dinv + node0 + kg * 4)
                            : make_float4(1.f, 1.f, 1.f, 1.f);
#pragma unroll
    for (int j = 0; j < 2; ++j) {
        int col = (wv * 2 + j) * 16 + m;
        float bv = bias[col];
#pragma unroll
        for (int r = 0; r < 4; ++r) {
            int row = node0 + kg * 4 + r;  // C/D: col=lane&15, row=(lane>>4)*4+reg
            float v = acc[j][r] + bv;
            v = v > 0.f ? v : 0.f;
            if (mode == 0)
                ((u16*)out)[(size_t)row * DIM + col] = f2bf(v * (&d4.x)[r]);
            else
                ((float*)out)[(size_t)row * DIM + col] = v;
        }
    }
}

extern "C" void kernel_launch(void* const* d_in, const int* in_sizes, int n_in,
                              void* d_out, int out_size, void* d_ws, size_t ws_size,
                              hipStream_t stream) {
    (void)in_sizes; (void)n_in; (void)out_size; (void)ws_size;
    const float* x  = (const float*)d_in[0];
    const int*   ei = (const int*)d_in[1];
    const float* W1 = (const float*)d_in[2];
    const float* b1 = (const float*)d_in[3];
    const float* W2 = (const float*)d_in[4];
    const float* b2 = (const float*)d_in[5];
    char* ws = (char*)d_ws;

    u16* W1t = (u16*)(ws + OFF_W1T);
    u16* W2t = (u16*)(ws + OFF_W2T);
    u32* y   = (u32*)(ws + OFF_Y);
    u32* z1  = (u32*)(ws + OFF_Z1);

    k_init<<<128, 256, 0, stream>>>(ei, W1, W2, ws);
    k_fill<<<(NE + 255) / 256, 256, 0, stream>>>(ei, ws);
    k_scale<<<NN * 32 / 256, 256, 0, stream>>>(x, ws);
    // layer 1: z1 = dinv * relu(Ahat(y) @ W1 + b1)   (bf16, pre-scaled)
    k_layer<<<NN / 16, 256, 0, stream>>>(y, ws, W1t, b1, z1, 0);
    // layer 2: out = relu(Ahat(z1) @ W2 + b2)        (f32)
    k_layer<<<NN / 16, 256, 0, stream>>>(z1, ws, W2t, b2, d_out, 1);
}